// Round 4
// baseline (642.685 us; speedup 1.0000x reference)
//
#include <hip/hip_runtime.h>

typedef short  short8  __attribute__((ext_vector_type(8)));
typedef short  short4v __attribute__((ext_vector_type(4)));
typedef float  float4v __attribute__((ext_vector_type(4)));
typedef int    int4v   __attribute__((ext_vector_type(4)));

#define LOG2E 1.4426950408889634f

static __device__ __forceinline__ short f2bf(float f) {
  unsigned u = __builtin_bit_cast(unsigned, f);
  u = (u + 0x7fffu + ((u >> 16) & 1u)) >> 16;   // RNE
  return (short)u;
}
static __device__ __forceinline__ float bf2f(short s) {
  return __builtin_bit_cast(float, ((unsigned)(unsigned short)s) << 16);
}

// ---------------------------------------------------------------------------
// Kernel 1: h = x @ w.T  (8192x256, K=256), hi/lo bf16-split MFMA for ~f32
// accuracy. Writes hT bf16 [256][8192] (ws) and hT f32 [256][8192] (d_out,
// transient scratch — k_gat overwrites d_out later).
// ---------------------------------------------------------------------------
__global__ __launch_bounds__(256) void k_hgemm(
    const float* __restrict__ x, const float* __restrict__ w,
    short* __restrict__ hT, float* __restrict__ hTf) {
  const int I0   = blockIdx.x * 64;
  const int lane = threadIdx.x & 63;
  const int wn   = threadIdx.x >> 6;       // 4 waves split N (cols)
  const int lrow = lane & 15;
  const int lk8  = (lane >> 4) << 3;

  float4v zero4 = {0.f, 0.f, 0.f, 0.f};
  float4v acc[4][4];
  #pragma unroll
  for (int mi = 0; mi < 4; ++mi)
    #pragma unroll
    for (int ni = 0; ni < 4; ++ni) acc[mi][ni] = zero4;

  for (int k0 = 0; k0 < 256; k0 += 32) {
    short8 ah[4], al[4], bh[4], bl[4];
    #pragma unroll
    for (int mi = 0; mi < 4; ++mi) {
      const float* xp = x + (size_t)(I0 + mi * 16 + lrow) * 256 + k0 + lk8;
      float4v va = *(const float4v*)xp;
      float4v vb = *(const float4v*)(xp + 4);
      #pragma unroll
      for (int e = 0; e < 4; ++e) {
        short h = f2bf(va[e]); ah[mi][e] = h;     al[mi][e]     = f2bf(va[e] - bf2f(h));
        h = f2bf(vb[e]);       ah[mi][4 + e] = h; al[mi][4 + e] = f2bf(vb[e] - bf2f(h));
      }
    }
    #pragma unroll
    for (int ni = 0; ni < 4; ++ni) {
      const float* wp = w + (size_t)(wn * 64 + ni * 16 + lrow) * 256 + k0 + lk8;
      float4v va = *(const float4v*)wp;
      float4v vb = *(const float4v*)(wp + 4);
      #pragma unroll
      for (int e = 0; e < 4; ++e) {
        short h = f2bf(va[e]); bh[ni][e] = h;     bl[ni][e]     = f2bf(va[e] - bf2f(h));
        h = f2bf(vb[e]);       bh[ni][4 + e] = h; bl[ni][4 + e] = f2bf(vb[e] - bf2f(h));
      }
    }
    #pragma unroll
    for (int mi = 0; mi < 4; ++mi)
      #pragma unroll
      for (int ni = 0; ni < 4; ++ni) {
        acc[mi][ni] = __builtin_amdgcn_mfma_f32_16x16x32_bf16(al[mi], bh[ni], acc[mi][ni], 0, 0, 0);
        acc[mi][ni] = __builtin_amdgcn_mfma_f32_16x16x32_bf16(ah[mi], bl[ni], acc[mi][ni], 0, 0, 0);
        acc[mi][ni] = __builtin_amdgcn_mfma_f32_16x16x32_bf16(ah[mi], bh[ni], acc[mi][ni], 0, 0, 0);
      }
  }
  const int r0 = (lane >> 4) << 2;   // C/D: col=lane&15, row=(lane>>4)*4+reg
  #pragma unroll
  for (int mi = 0; mi < 4; ++mi)
    #pragma unroll
    for (int ni = 0; ni < 4; ++ni) {
      const int c   = wn * 64 + ni * 16 + lrow;
      const int row = I0 + mi * 16 + r0;
      float4v v = acc[mi][ni];
      short4v sv;
      #pragma unroll
      for (int r = 0; r < 4; ++r) sv[r] = f2bf(v[r]);
      *(short4v*)(hT + (size_t)c * 8192 + row) = sv;
      *(float4v*)(hTf + (size_t)c * 8192 + row) = v;
    }
}

// ---------------------------------------------------------------------------
// Kernel 2: s1 = h@a1, s2 = h@a2 partials (split-K = 2)
// ---------------------------------------------------------------------------
__global__ __launch_bounds__(256) void k_scores1(
    const float* __restrict__ hTf, const float* __restrict__ a,
    float* __restrict__ t1p, float* __restrict__ t2p) {
  const int i = blockIdx.x * 256 + threadIdx.x;
  const int q = blockIdx.y;
  float s1 = 0.f, s2 = 0.f;
  #pragma unroll 8
  for (int kf = q * 128; kf < q * 128 + 128; ++kf) {
    float hv = hTf[(size_t)kf * 8192 + i];
    s1 = fmaf(hv, a[kf], s1);
    s2 = fmaf(hv, a[256 + kf], s2);
  }
  t1p[q * 8192 + i] = s1;
  t2p[q * 8192 + i] = s2;
}

// ---------------------------------------------------------------------------
// Kernel 3: reduce partials, emit exp2 tables:
//   e1f1[i] = {exp2(t1c), exp2(0.2 t1c)},  ef2[j] = {exp2(t2c), exp2(0.2 t2c)}
// so W = adj ? max(e1*e2, f1*f2) : 1   (exp2(max(sc,0.2sc)) separable via
// monotonicity of exp2 — no per-element transcendental in k_gat).
// ---------------------------------------------------------------------------
__global__ __launch_bounds__(256) void k_scores2(
    const float* __restrict__ t1p, const float* __restrict__ t2p,
    float2* __restrict__ e1f1, float2* __restrict__ ef2) {
  const int i = blockIdx.x * 256 + threadIdx.x;
  const float t1 = LOG2E * (t1p[i] + t1p[8192 + i]);
  const float t2 = LOG2E * (t2p[i] + t2p[8192 + i]);
  e1f1[i] = make_float2(exp2f(t1), exp2f(0.2f * t1));
  ef2[i]  = make_float2(exp2f(t2), exp2f(0.2f * t2));
}

// ---------------------------------------------------------------------------
// Kernel 4: fused GAT body — barrier-free, zero LDS, straight-line named-reg
// software pipeline (no arrays -> no scratch demotion).
// Grid 256 x 512 threads; 8 waves = 2m x 4n; wave: 16 rows x 64 cols, K=8192
// in 256 steps of 32 j. Unroll-by-4 main loop: adj in 4 named slot-sets
// (prefetch distance 4, covers L3 latency), B/ef in parity (E/O) slots
// (distance 2, L2-hot). 5 MFMAs/step: 4 x N-accum + 1 x Z (B=ones, Z lands
// in the exact C-layout rows for the epilogue divide).
// ---------------------------------------------------------------------------
__global__ __launch_bounds__(512) void k_gat(
    const int* __restrict__ adj, const short* __restrict__ hT,
    const float2* __restrict__ e1f1, const float* __restrict__ ef2,
    float* __restrict__ out) {
  const int tid = threadIdx.x, lane = tid & 63, wave = tid >> 6;
  const int wm = wave >> 2, wn = wave & 3;
  const int lrow = lane & 15, lk8 = (lane >> 4) << 3;
  const int I0 = blockIdx.x * 32;
  const int row = I0 + wm * 16 + lrow;

  const int* arow = adj + (size_t)row * 8192 + lk8;
  const float4v* ef4 = (const float4v*)ef2;   // float4v idx = j/2
  const int efbase = lk8 >> 1;
  const short* bp0 = hT + (size_t)(wn * 64 + lrow) * 8192 + lk8;
  const short* bp1 = bp0 + (size_t)16 * 8192;
  const short* bp2 = bp0 + (size_t)32 * 8192;
  const short* bp3 = bp0 + (size_t)48 * 8192;

  const float2 ef1v = e1f1[row];
  const float e1 = ef1v.x, f1 = ef1v.y;

  short8 bone;
  #pragma unroll
  for (int e = 0; e < 8; ++e) bone[e] = (short)0x3F80;   // bf16 1.0

  float4v zero4 = {0.f, 0.f, 0.f, 0.f};
  float4v acc0 = zero4, acc1 = zero4, acc2 = zero4, acc3 = zero4;
  float4v accz = zero4;

  // prologue: adj steps 0..3 (4 slot-sets), ef/B for steps 0 (E) and 1 (O)
  int4v adjA0 = __builtin_nontemporal_load((const int4v*)(arow));
  int4v adjA1 = __builtin_nontemporal_load((const int4v*)(arow + 4));
  int4v adjB0 = __builtin_nontemporal_load((const int4v*)(arow + 32));
  int4v adjB1 = __builtin_nontemporal_load((const int4v*)(arow + 36));
  int4v adjC0 = __builtin_nontemporal_load((const int4v*)(arow + 64));
  int4v adjC1 = __builtin_nontemporal_load((const int4v*)(arow + 68));
  int4v adjD0 = __builtin_nontemporal_load((const int4v*)(arow + 96));
  int4v adjD1 = __builtin_nontemporal_load((const int4v*)(arow + 100));

  float4v efE0 = ef4[efbase],      efE1 = ef4[efbase + 1];
  float4v efE2 = ef4[efbase + 2],  efE3 = ef4[efbase + 3];
  float4v efO0 = ef4[efbase + 16], efO1 = ef4[efbase + 17];
  float4v efO2 = ef4[efbase + 18], efO3 = ef4[efbase + 19];

  short8 bE0 = *(const short8*)(bp0), bE1 = *(const short8*)(bp1);
  short8 bE2 = *(const short8*)(bp2), bE3 = *(const short8*)(bp3);
  short8 bO0 = *(const short8*)(bp0 + 32), bO1 = *(const short8*)(bp1 + 32);
  short8 bO2 = *(const short8*)(bp2 + 32), bO3 = *(const short8*)(bp3 + 32);

#define WELEM(EF, A0, A1, DST)                                               \
  { float wA_ = fmaxf(e1 * (EF)[0], f1 * (EF)[1]);                           \
    float wB_ = fmaxf(e1 * (EF)[2], f1 * (EF)[3]);                           \
    wA_ = (A0) ? wA_ : 1.0f;  wB_ = (A1) ? wB_ : 1.0f;                       \
    asm("v_cvt_pk_bf16_f32 %0, %1, %2" : "=v"(DST) : "v"(wA_), "v"(wB_)); }

#define BODY(AS, P, SCUR)                                                    \
  {                                                                          \
    int4v pwi;                                                               \
    WELEM(ef##P##0, adj##AS##0[0], adj##AS##0[1], pwi[0]);                   \
    WELEM(ef##P##1, adj##AS##0[2], adj##AS##0[3], pwi[1]);                   \
    WELEM(ef##P##2, adj##AS##1[0], adj##AS##1[1], pwi[2]);                   \
    WELEM(ef##P##3, adj##AS##1[2], adj##AS##1[3], pwi[3]);                   \
    const int ja_ = (((SCUR) + 4) * 32) & 8191;                              \
    adj##AS##0 = __builtin_nontemporal_load((const int4v*)(arow + ja_));     \
    adj##AS##1 = __builtin_nontemporal_load((const int4v*)(arow + ja_ + 4)); \
    const int je_ = (((SCUR) + 2) * 32) & 8191;                              \
    const int ei_ = (je_ >> 1) + efbase;                                     \
    ef##P##0 = ef4[ei_];      ef##P##1 = ef4[ei_ + 1];                       \
    ef##P##2 = ef4[ei_ + 2];  ef##P##3 = ef4[ei_ + 3];                       \
    const short8 af_ = __builtin_bit_cast(short8, pwi);                      \
    accz = __builtin_amdgcn_mfma_f32_16x16x32_bf16(af_, bone, accz, 0, 0, 0);\
    acc0 = __builtin_amdgcn_mfma_f32_16x16x32_bf16(af_, b##P##0, acc0, 0, 0, 0); \
    acc1 = __builtin_amdgcn_mfma_f32_16x16x32_bf16(af_, b##P##1, acc1, 0, 0, 0); \
    acc2 = __builtin_amdgcn_mfma_f32_16x16x32_bf16(af_, b##P##2, acc2, 0, 0, 0); \
    acc3 = __builtin_amdgcn_mfma_f32_16x16x32_bf16(af_, b##P##3, acc3, 0, 0, 0); \
    b##P##0 = *(const short8*)(bp0 + je_);                                   \
    b##P##1 = *(const short8*)(bp1 + je_);                                   \
    b##P##2 = *(const short8*)(bp2 + je_);                                   \
    b##P##3 = *(const short8*)(bp3 + je_);                                   \
  }

  for (int s = 0; s < 256; s += 4) {
    BODY(A, E, s + 0);
    BODY(B, O, s + 1);
    BODY(C, E, s + 2);
    BODY(D, O, s + 3);
  }
#undef BODY
#undef WELEM

  // epilogue: out = elu(N/Z); accz[r] is Z for C/D row (lane>>4)*4+r
  float rz0 = 1.0f / accz[0], rz1 = 1.0f / accz[1];
  float rz2 = 1.0f / accz[2], rz3 = 1.0f / accz[3];
  const int orow0 = I0 + wm * 16 + ((lane >> 4) << 2);
  #pragma unroll
  for (int ni = 0; ni < 4; ++ni) {
    const int col = wn * 64 + ni * 16 + lrow;
    const float4v av = (ni == 0) ? acc0 : (ni == 1) ? acc1 : (ni == 2) ? acc2 : acc3;
    float v0 = av[0] * rz0, v1 = av[1] * rz1, v2 = av[2] * rz2, v3 = av[3] * rz3;
    out[(size_t)(orow0 + 0) * 256 + col] = (v0 > 0.f) ? v0 : expm1f(v0);
    out[(size_t)(orow0 + 1) * 256 + col] = (v1 > 0.f) ? v1 : expm1f(v1);
    out[(size_t)(orow0 + 2) * 256 + col] = (v2 > 0.f) ? v2 : expm1f(v2);
    out[(size_t)(orow0 + 3) * 256 + col] = (v3 > 0.f) ? v3 : expm1f(v3);
  }
}

// ---------------------------------------------------------------------------
extern "C" void kernel_launch(void* const* d_in, const int* in_sizes, int n_in,
                              void* d_out, int out_size, void* d_ws, size_t ws_size,
                              hipStream_t stream) {
  const int*   adj = (const int*)d_in[0];
  const float* x   = (const float*)d_in[1];
  const float* w   = (const float*)d_in[2];
  const float* a   = (const float*)d_in[3];
  float* out = (float*)d_out;

  // ws usage: 4 MiB + 256 KiB (within the 4.5 MiB proven-safe bound).
  // hTf (8 MiB f32) lives in d_out transiently; k_gat overwrites d_out.
  char* ws = (char*)d_ws;
  short*  hT   = (short*)(ws + 0);          // 4 MiB  bf16 h^T [256][8192]
  float*  t1p  = (float*)(ws + 4194304);    // 64 KiB (2 x 8192)
  float*  t2p  = (float*)(ws + 4259840);    // 64 KiB
  float2* e1f1 = (float2*)(ws + 4325376);   // 64 KiB
  float2* ef2  = (float2*)(ws + 4390912);   // 64 KiB
  float*  hTf  = (float*)d_out;             // 8 MiB  f32 h^T (transient)

  k_hgemm  <<<128, 256, 0, stream>>>(x, w, hT, hTf);
  k_scores1<<<dim3(32, 2), 256, 0, stream>>>(hTf, a, t1p, t2p);
  k_scores2<<<32, 256, 0, stream>>>(t1p, t2p, e1f1, ef2);
  k_gat    <<<256, 512, 0, stream>>>(adj, hT, e1f1, (const float*)ef2, out);
}

// Round 5
// 521.252 us; speedup vs baseline: 1.2330x; 1.2330x over previous
//
#include <hip/hip_runtime.h>

typedef short  short8  __attribute__((ext_vector_type(8)));
typedef short  short4v __attribute__((ext_vector_type(4)));
typedef float  float4v __attribute__((ext_vector_type(4)));
typedef int    int4v   __attribute__((ext_vector_type(4)));

#define LOG2E 1.4426950408889634f

static __device__ __forceinline__ short f2bf(float f) {
  unsigned u = __builtin_bit_cast(unsigned, f);
  u = (u + 0x7fffu + ((u >> 16) & 1u)) >> 16;   // RNE
  return (short)u;
}
static __device__ __forceinline__ float bf2f(short s) {
  return __builtin_bit_cast(float, ((unsigned)(unsigned short)s) << 16);
}

// ---------------------------------------------------------------------------
// Kernel 1: h = x @ w.T  (8192x256, K=256), hi/lo bf16-split MFMA for ~f32
// accuracy. Writes hT bf16 [256][8192] (ws) and hT f32 [256][8192] (d_out,
// transient scratch — consumed by k_scores1, then d_out is zeroed for k_gat).
// ---------------------------------------------------------------------------
__global__ __launch_bounds__(256) void k_hgemm(
    const float* __restrict__ x, const float* __restrict__ w,
    short* __restrict__ hT, float* __restrict__ hTf) {
  const int I0   = blockIdx.x * 64;
  const int lane = threadIdx.x & 63;
  const int wn   = threadIdx.x >> 6;       // 4 waves split N (cols)
  const int lrow = lane & 15;
  const int lk8  = (lane >> 4) << 3;

  float4v zero4 = {0.f, 0.f, 0.f, 0.f};
  float4v acc[4][4];
  #pragma unroll
  for (int mi = 0; mi < 4; ++mi)
    #pragma unroll
    for (int ni = 0; ni < 4; ++ni) acc[mi][ni] = zero4;

  for (int k0 = 0; k0 < 256; k0 += 32) {
    short8 ah[4], al[4], bh[4], bl[4];
    #pragma unroll
    for (int mi = 0; mi < 4; ++mi) {
      const float* xp = x + (size_t)(I0 + mi * 16 + lrow) * 256 + k0 + lk8;
      float4v va = *(const float4v*)xp;
      float4v vb = *(const float4v*)(xp + 4);
      #pragma unroll
      for (int e = 0; e < 4; ++e) {
        short h = f2bf(va[e]); ah[mi][e] = h;     al[mi][e]     = f2bf(va[e] - bf2f(h));
        h = f2bf(vb[e]);       ah[mi][4 + e] = h; al[mi][4 + e] = f2bf(vb[e] - bf2f(h));
      }
    }
    #pragma unroll
    for (int ni = 0; ni < 4; ++ni) {
      const float* wp = w + (size_t)(wn * 64 + ni * 16 + lrow) * 256 + k0 + lk8;
      float4v va = *(const float4v*)wp;
      float4v vb = *(const float4v*)(wp + 4);
      #pragma unroll
      for (int e = 0; e < 4; ++e) {
        short h = f2bf(va[e]); bh[ni][e] = h;     bl[ni][e]     = f2bf(va[e] - bf2f(h));
        h = f2bf(vb[e]);       bh[ni][4 + e] = h; bl[ni][4 + e] = f2bf(vb[e] - bf2f(h));
      }
    }
    #pragma unroll
    for (int mi = 0; mi < 4; ++mi)
      #pragma unroll
      for (int ni = 0; ni < 4; ++ni) {
        acc[mi][ni] = __builtin_amdgcn_mfma_f32_16x16x32_bf16(al[mi], bh[ni], acc[mi][ni], 0, 0, 0);
        acc[mi][ni] = __builtin_amdgcn_mfma_f32_16x16x32_bf16(ah[mi], bl[ni], acc[mi][ni], 0, 0, 0);
        acc[mi][ni] = __builtin_amdgcn_mfma_f32_16x16x32_bf16(ah[mi], bh[ni], acc[mi][ni], 0, 0, 0);
      }
  }
  const int r0 = (lane >> 4) << 2;   // C/D: col=lane&15, row=(lane>>4)*4+reg
  #pragma unroll
  for (int mi = 0; mi < 4; ++mi)
    #pragma unroll
    for (int ni = 0; ni < 4; ++ni) {
      const int c   = wn * 64 + ni * 16 + lrow;
      const int row = I0 + mi * 16 + r0;
      float4v v = acc[mi][ni];
      short4v sv;
      #pragma unroll
      for (int r = 0; r < 4; ++r) sv[r] = f2bf(v[r]);
      *(short4v*)(hT + (size_t)c * 8192 + row) = sv;
      *(float4v*)(hTf + (size_t)c * 8192 + row) = v;
    }
}

// ---------------------------------------------------------------------------
// Kernel 2: s1 = h@a1, s2 = h@a2 partials (split-K = 2)
// ---------------------------------------------------------------------------
__global__ __launch_bounds__(256) void k_scores1(
    const float* __restrict__ hTf, const float* __restrict__ a,
    float* __restrict__ t1p, float* __restrict__ t2p) {
  const int i = blockIdx.x * 256 + threadIdx.x;
  const int q = blockIdx.y;
  float s1 = 0.f, s2 = 0.f;
  #pragma unroll 8
  for (int kf = q * 128; kf < q * 128 + 128; ++kf) {
    float hv = hTf[(size_t)kf * 8192 + i];
    s1 = fmaf(hv, a[kf], s1);
    s2 = fmaf(hv, a[256 + kf], s2);
  }
  t1p[q * 8192 + i] = s1;
  t2p[q * 8192 + i] = s2;
}

// ---------------------------------------------------------------------------
// Kernel 3: reduce partials, emit exp2 tables:
//   e1f1[i] = {exp2(t1c), exp2(0.2 t1c)},  ef2[j] = {exp2(t2c), exp2(0.2 t2c)}
// so W = adj ? max(e1*e2, f1*f2) : 1   (exp2(max(sc,0.2sc)) separable via
// monotonicity of exp2 — no per-element transcendental in k_gat).
// ---------------------------------------------------------------------------
__global__ __launch_bounds__(256) void k_scores2(
    const float* __restrict__ t1p, const float* __restrict__ t2p,
    float2* __restrict__ e1f1, float2* __restrict__ ef2) {
  const int i = blockIdx.x * 256 + threadIdx.x;
  const float t1 = LOG2E * (t1p[i] + t1p[8192 + i]);
  const float t2 = LOG2E * (t2p[i] + t2p[8192 + i]);
  e1f1[i] = make_float2(exp2f(t1), exp2f(0.2f * t1));
  ef2[i]  = make_float2(exp2f(t2), exp2f(0.2f * t2));
}

// ---------------------------------------------------------------------------
// Kernel 4: fused GAT body — zero LDS, zero barriers, NO manual pipelining
// (compiler defeats it: r3 scratch-demotion, r4 load-sinking). Latency is
// hidden by occupancy instead: split-K=4 -> grid (256,4) = 1024 blocks,
// launch_bounds(512,4) caps VGPR at 128 -> 2 blocks/CU resident (16 waves).
// Per block: 32 rows x 2048 j in 64 steps of 32 j. Per step/wave: A-frag
// (W tile) built in regs from per-lane adj + ef2 table loads; 1 Z-MFMA
// (B=ones) + 4 N-MFMAs. Partials combined via f32 atomicAdd (N into d_out,
// Z into ws).
// ---------------------------------------------------------------------------
__global__ __launch_bounds__(512, 4) void k_gat(
    const int* __restrict__ adj, const short* __restrict__ hT,
    const float2* __restrict__ e1f1, const float* __restrict__ ef2,
    float* __restrict__ Nout, float* __restrict__ Zp) {
  const int tid = threadIdx.x, lane = tid & 63, wave = tid >> 6;
  const int wm = wave >> 2, wn = wave & 3;
  const int lrow = lane & 15, lk8 = (lane >> 4) << 3;
  const int I0 = blockIdx.x * 32;
  const int row = I0 + wm * 16 + lrow;
  const int j0 = blockIdx.y * 2048;

  const int* arow = adj + (size_t)row * 8192 + j0 + lk8;
  const float4v* ef4 = (const float4v*)ef2;     // float4v index = j/2
  const int efbase = (j0 + lk8) >> 1;
  const short* bp[4];
  #pragma unroll
  for (int ni = 0; ni < 4; ++ni)
    bp[ni] = hT + (size_t)(wn * 64 + ni * 16 + lrow) * 8192 + j0 + lk8;

  const float2 ef1v = e1f1[row];
  const float e1 = ef1v.x, f1 = ef1v.y;

  short8 bone;
  #pragma unroll
  for (int e = 0; e < 8; ++e) bone[e] = (short)0x3F80;   // bf16 1.0

  float4v zero4 = {0.f, 0.f, 0.f, 0.f};
  float4v acc[4] = {zero4, zero4, zero4, zero4};
  float4v accz = zero4;

  #pragma unroll 2
  for (int s = 0; s < 64; ++s) {
    const int jb = s * 32;
    const int4v a0 = __builtin_nontemporal_load((const int4v*)(arow + jb));
    const int4v a1 = __builtin_nontemporal_load((const int4v*)(arow + jb + 4));
    const int ei = (jb >> 1) + efbase;
    const float4v ef0 = ef4[ei],     ef1_ = ef4[ei + 1];
    const float4v ef2_ = ef4[ei + 2], ef3 = ef4[ei + 3];

    int4v pwi;
#define WELEM(EF, A0, A1, DST)                                               \
    { float wA_ = fmaxf(e1 * (EF)[0], f1 * (EF)[1]);                         \
      float wB_ = fmaxf(e1 * (EF)[2], f1 * (EF)[3]);                         \
      wA_ = (A0) ? wA_ : 1.0f;  wB_ = (A1) ? wB_ : 1.0f;                     \
      asm("v_cvt_pk_bf16_f32 %0, %1, %2" : "=v"(DST) : "v"(wA_), "v"(wB_)); }
    WELEM(ef0,  a0[0], a0[1], pwi[0]);
    WELEM(ef1_, a0[2], a0[3], pwi[1]);
    WELEM(ef2_, a1[0], a1[1], pwi[2]);
    WELEM(ef3,  a1[2], a1[3], pwi[3]);
#undef WELEM
    const short8 af = __builtin_bit_cast(short8, pwi);

    accz = __builtin_amdgcn_mfma_f32_16x16x32_bf16(af, bone, accz, 0, 0, 0);
    #pragma unroll
    for (int ni = 0; ni < 4; ++ni) {
      const short8 b = *(const short8*)(bp[ni] + jb);
      acc[ni] = __builtin_amdgcn_mfma_f32_16x16x32_bf16(af, b, acc[ni], 0, 0, 0);
    }
  }

  // accumulate partials: N via atomicAdd into d_out, Z into Zp (wn==0 only;
  // accz cols are identical since B=ones -> contribute from lrow==0 lanes).
  const int orow0 = I0 + wm * 16 + ((lane >> 4) << 2);
  #pragma unroll
  for (int ni = 0; ni < 4; ++ni) {
    const int col = wn * 64 + ni * 16 + lrow;
    #pragma unroll
    for (int r = 0; r < 4; ++r)
      atomicAdd(&Nout[(size_t)(orow0 + r) * 256 + col], acc[ni][r]);
  }
  if (wn == 0 && lrow == 0) {
    #pragma unroll
    for (int r = 0; r < 4; ++r)
      atomicAdd(&Zp[orow0 + r], accz[r]);
  }
}

// ---------------------------------------------------------------------------
// Kernel 5: in-place epilogue on d_out: out = elu(N/Z)
// ---------------------------------------------------------------------------
__global__ __launch_bounds__(256) void k_out(
    float* __restrict__ Nout, const float* __restrict__ Zp) {
  const int idx = blockIdx.x * 256 + threadIdx.x;   // float4 index
  const int i = idx >> 6;                           // row (256 feat = 64 f4)
  const float rz = 1.0f / Zp[i];
  float4v n = ((const float4v*)Nout)[idx];
  float4v o;
  #pragma unroll
  for (int e = 0; e < 4; ++e) {
    float v = n[e] * rz;
    o[e] = (v > 0.f) ? v : expm1f(v);
  }
  ((float4v*)Nout)[idx] = o;
}

// ---------------------------------------------------------------------------
extern "C" void kernel_launch(void* const* d_in, const int* in_sizes, int n_in,
                              void* d_out, int out_size, void* d_ws, size_t ws_size,
                              hipStream_t stream) {
  const int*   adj = (const int*)d_in[0];
  const float* x   = (const float*)d_in[1];
  const float* w   = (const float*)d_in[2];
  const float* a   = (const float*)d_in[3];

  // ws usage: ~4.3 MiB (within the proven-safe bound).
  // hTf (8 MiB f32) lives in d_out transiently; d_out is then zeroed and
  // used as the f32 N accumulator, finished in place by k_out.
  char* ws = (char*)d_ws;
  short*  hT   = (short*)(ws + 0);          // 4 MiB  bf16 h^T [256][8192]
  float*  t1p  = (float*)(ws + 4194304);    // 64 KiB (2 x 8192)
  float*  t2p  = (float*)(ws + 4259840);    // 64 KiB
  float2* e1f1 = (float2*)(ws + 4325376);   // 64 KiB
  float2* ef2  = (float2*)(ws + 4390912);   // 64 KiB
  float*  Zp   = (float*)(ws + 4456448);    // 32 KiB
  float*  hTf  = (float*)d_out;             // 8 MiB  f32 h^T (transient)
  float*  Nout = (float*)d_out;             // then f32 N accumulator

  k_hgemm  <<<128, 256, 0, stream>>>(x, w, hT, hTf);
  k_scores1<<<dim3(32, 2), 256, 0, stream>>>(hTf, a, t1p, t2p);
  k_scores2<<<32, 256, 0, stream>>>(t1p, t2p, e1f1, ef2);
  hipMemsetAsync(d_out, 0, (size_t)out_size * 4, stream);
  hipMemsetAsync(Zp, 0, 32768, stream);
  k_gat    <<<dim3(256, 4), 512, 0, stream>>>(adj, hT, e1f1, (const float*)ef2, Nout, Zp);
  k_out    <<<2048, 256, 0, stream>>>(Nout, Zp);
}

// Round 6
// 158.302 us; speedup vs baseline: 4.0599x; 3.2928x over previous
//
#include <hip/hip_runtime.h>

typedef short  short8  __attribute__((ext_vector_type(8)));
typedef short  short4v __attribute__((ext_vector_type(4)));
typedef float  float4v __attribute__((ext_vector_type(4)));
typedef int    int4v   __attribute__((ext_vector_type(4)));
typedef int    int2v   __attribute__((ext_vector_type(2)));

#define LOG2E 1.4426950408889634f

static __device__ __forceinline__ short f2bf(float f) {
  unsigned u = __builtin_bit_cast(unsigned, f);
  u = (u + 0x7fffu + ((u >> 16) & 1u)) >> 16;   // RNE
  return (short)u;
}
static __device__ __forceinline__ float bf2f(short s) {
  return __builtin_bit_cast(float, ((unsigned)(unsigned short)s) << 16);
}

// ---------------------------------------------------------------------------
// Kernel 1: h = x @ w.T  (8192x256, K=256), hi/lo bf16-split MFMA for ~f32
// accuracy. Writes hT bf16 [256][8192] (ws) and hT f32 [256][8192] (d_out,
// transient — consumed by k_scores1, then d_out is zeroed for k_gat).
// ---------------------------------------------------------------------------
__global__ __launch_bounds__(256) void k_hgemm(
    const float* __restrict__ x, const float* __restrict__ w,
    short* __restrict__ hT, float* __restrict__ hTf) {
  const int I0   = blockIdx.x * 64;
  const int lane = threadIdx.x & 63;
  const int wn   = threadIdx.x >> 6;       // 4 waves split N (cols)
  const int lrow = lane & 15;
  const int lk8  = (lane >> 4) << 3;

  float4v zero4 = {0.f, 0.f, 0.f, 0.f};
  float4v acc[4][4];
  #pragma unroll
  for (int mi = 0; mi < 4; ++mi)
    #pragma unroll
    for (int ni = 0; ni < 4; ++ni) acc[mi][ni] = zero4;

  for (int k0 = 0; k0 < 256; k0 += 32) {
    short8 ah[4], al[4], bh[4], bl[4];
    #pragma unroll
    for (int mi = 0; mi < 4; ++mi) {
      const float* xp = x + (size_t)(I0 + mi * 16 + lrow) * 256 + k0 + lk8;
      float4v va = *(const float4v*)xp;
      float4v vb = *(const float4v*)(xp + 4);
      #pragma unroll
      for (int e = 0; e < 4; ++e) {
        short h = f2bf(va[e]); ah[mi][e] = h;     al[mi][e]     = f2bf(va[e] - bf2f(h));
        h = f2bf(vb[e]);       ah[mi][4 + e] = h; al[mi][4 + e] = f2bf(vb[e] - bf2f(h));
      }
    }
    #pragma unroll
    for (int ni = 0; ni < 4; ++ni) {
      const float* wp = w + (size_t)(wn * 64 + ni * 16 + lrow) * 256 + k0 + lk8;
      float4v va = *(const float4v*)wp;
      float4v vb = *(const float4v*)(wp + 4);
      #pragma unroll
      for (int e = 0; e < 4; ++e) {
        short h = f2bf(va[e]); bh[ni][e] = h;     bl[ni][e]     = f2bf(va[e] - bf2f(h));
        h = f2bf(vb[e]);       bh[ni][4 + e] = h; bl[ni][4 + e] = f2bf(vb[e] - bf2f(h));
      }
    }
    #pragma unroll
    for (int mi = 0; mi < 4; ++mi)
      #pragma unroll
      for (int ni = 0; ni < 4; ++ni) {
        acc[mi][ni] = __builtin_amdgcn_mfma_f32_16x16x32_bf16(al[mi], bh[ni], acc[mi][ni], 0, 0, 0);
        acc[mi][ni] = __builtin_amdgcn_mfma_f32_16x16x32_bf16(ah[mi], bl[ni], acc[mi][ni], 0, 0, 0);
        acc[mi][ni] = __builtin_amdgcn_mfma_f32_16x16x32_bf16(ah[mi], bh[ni], acc[mi][ni], 0, 0, 0);
      }
  }
  const int r0 = (lane >> 4) << 2;   // C/D: col=lane&15, row=(lane>>4)*4+reg
  #pragma unroll
  for (int mi = 0; mi < 4; ++mi)
    #pragma unroll
    for (int ni = 0; ni < 4; ++ni) {
      const int c   = wn * 64 + ni * 16 + lrow;
      const int row = I0 + mi * 16 + r0;
      float4v v = acc[mi][ni];
      short4v sv;
      #pragma unroll
      for (int r = 0; r < 4; ++r) sv[r] = f2bf(v[r]);
      *(short4v*)(hT + (size_t)c * 8192 + row) = sv;
      *(float4v*)(hTf + (size_t)c * 8192 + row) = v;
    }
}

// ---------------------------------------------------------------------------
// Kernel 2: s1 = h@a1, s2 = h@a2 partials (split-K = 2)
// ---------------------------------------------------------------------------
__global__ __launch_bounds__(256) void k_scores1(
    const float* __restrict__ hTf, const float* __restrict__ a,
    float* __restrict__ t1p, float* __restrict__ t2p) {
  const int i = blockIdx.x * 256 + threadIdx.x;
  const int q = blockIdx.y;
  float s1 = 0.f, s2 = 0.f;
  #pragma unroll 8
  for (int kf = q * 128; kf < q * 128 + 128; ++kf) {
    float hv = hTf[(size_t)kf * 8192 + i];
    s1 = fmaf(hv, a[kf], s1);
    s2 = fmaf(hv, a[256 + kf], s2);
  }
  t1p[q * 8192 + i] = s1;
  t2p[q * 8192 + i] = s2;
}

// ---------------------------------------------------------------------------
// Kernel 3: reduce partials, emit exp2 tables:
//   e1f1[i] = {exp2(t1c), exp2(0.2 t1c)},  ef2[j] = {exp2(t2c), exp2(0.2 t2c)}
// so W = adj ? max(e1*e2, f1*f2) : 1   (exp2(max(sc,0.2sc)) separable via
// monotonicity of exp2 — no per-element transcendental in k_gat).
// ---------------------------------------------------------------------------
__global__ __launch_bounds__(256) void k_scores2(
    const float* __restrict__ t1p, const float* __restrict__ t2p,
    float2* __restrict__ e1f1, float2* __restrict__ ef2) {
  const int i = blockIdx.x * 256 + threadIdx.x;
  const float t1 = LOG2E * (t1p[i] + t1p[8192 + i]);
  const float t2 = LOG2E * (t2p[i] + t2p[8192 + i]);
  e1f1[i] = make_float2(exp2f(t1), exp2f(0.2f * t1));
  ef2[i]  = make_float2(exp2f(t2), exp2f(0.2f * t2));
}

// ---------------------------------------------------------------------------
// Kernel 4: fused GAT GEMM. All global loads line-coalesced (the r2/r5
// bottleneck was TA segment throughput from per-lane gathers); the lane-
// scatter MFMA frags need happens in LDS (free). BM=128 x BN=256 x BK=64,
// split-K=4: grid (64,4), 512 threads = 8 waves (2wm x 4wn), 4mi x 4ni acc.
// Per step: stage adj-tile (32KB) + hT-tile (32KB) coalesced; W = adj ?
// max(e1*e2, f1*f2) : 1 computed in regs -> bf16 -> XOR-swizzled LDS;
// swizzled ds_read_b128 frags; 32 MFMA/wave + Z-MFMA (B=ones) on wn==0.
// Next-step globals issued right after the tiles-ready barrier (latency
// hides under the LDS/MFMA phase). Split-K partials via f32 atomicAdd.
// ---------------------------------------------------------------------------
__global__ __launch_bounds__(512) void k_gat(
    const int* __restrict__ adj, const short* __restrict__ hT,
    const float2* __restrict__ e1f1, const float2* __restrict__ ef2,
    float* __restrict__ Nout, float* __restrict__ Zp) {
  __shared__ __align__(16) char Wt[16384];   // [128 rows][64 j] bf16, swizzled
  __shared__ __align__(16) char Ht[32768];   // [256 f][64 j] bf16, swizzled

  const int tid = threadIdx.x, lane = tid & 63, wave = tid >> 6;
  const int wm = wave >> 2, wn = wave & 3;
  const int lrow = lane & 15, lk8 = (lane >> 4) << 3;
  const int I0 = blockIdx.x * 128;
  const int j0 = blockIdx.y * 2048;

  // staging maps (4 passes each; pass p adds 32 adj-rows / 64 hT-rows)
  const int arow = tid >> 4;              // adj local row 0..31
  const int ajc  = (tid & 15) * 4;        // 4-j chunk
  const int hfl  = tid >> 3;              // hT local f 0..63
  const int hjc  = (tid & 7) * 8;         // 8-j chunk

  const int*    agp = adj + (size_t)(I0 + arow) * 8192 + j0 + ajc;
  const short*  hgp = hT + (size_t)hfl * 8192 + j0 + hjc;
  const float2* efp = ef2 + j0 + ajc;

  float e1p[4], f1p[4];
  #pragma unroll
  for (int p = 0; p < 4; ++p) {
    float2 v = e1f1[I0 + p * 32 + arow];
    e1p[p] = v.x; f1p[p] = v.y;
  }

  char* wwr = Wt + arow * 128 + ((ajc * 2) ^ ((arow & 7) << 4));
  char* hwr = Ht + hfl * 128 + ((hjc * 2) ^ ((hfl & 7) << 4));

  const int fswz = (lrow & 7) << 4;
  const char* ard = Wt + (wm * 64 + lrow) * 128;
  const char* brd = Ht + (wn * 64 + lrow) * 128;

  short8 bone;
  #pragma unroll
  for (int e = 0; e < 8; ++e) bone[e] = (short)0x3F80;   // bf16 1.0

  float4v zero4 = {0.f, 0.f, 0.f, 0.f};
  float4v acc[4][4];
  #pragma unroll
  for (int mi = 0; mi < 4; ++mi)
    #pragma unroll
    for (int ni = 0; ni < 4; ++ni) acc[mi][ni] = zero4;
  float4v accz[4] = {zero4, zero4, zero4, zero4};

  // prefetch registers (step 0)
  int4v  ga[4];
  short8 gh[4];
  float4v ge0, ge1;
  #pragma unroll
  for (int p = 0; p < 4; ++p) {
    ga[p] = __builtin_nontemporal_load((const int4v*)(agp + (size_t)p * 262144));
    gh[p] = *(const short8*)(hgp + (size_t)p * 524288);
  }
  ge0 = *(const float4v*)(efp);
  ge1 = *(const float4v*)(efp + 2);

  for (int s = 0; s < 32; ++s) {
    // W-compute (regs) for the staged adj chunk
    int2v pw[4];
    #pragma unroll
    for (int p = 0; p < 4; ++p) {
      float w0 = ga[p][0] ? fmaxf(e1p[p] * ge0[0], f1p[p] * ge0[1]) : 1.0f;
      float w1 = ga[p][1] ? fmaxf(e1p[p] * ge0[2], f1p[p] * ge0[3]) : 1.0f;
      float w2 = ga[p][2] ? fmaxf(e1p[p] * ge1[0], f1p[p] * ge1[1]) : 1.0f;
      float w3 = ga[p][3] ? fmaxf(e1p[p] * ge1[2], f1p[p] * ge1[3]) : 1.0f;
      asm("v_cvt_pk_bf16_f32 %0, %1, %2" : "=v"(pw[p][0]) : "v"(w0), "v"(w1));
      asm("v_cvt_pk_bf16_f32 %0, %1, %2" : "=v"(pw[p][1]) : "v"(w2), "v"(w3));
    }
    __syncthreads();                       // previous step's frag reads done
    #pragma unroll
    for (int p = 0; p < 4; ++p) {
      *(int2v*)(wwr + p * 4096) = pw[p];   // ds_write_b64, swizzled
      *(short8*)(hwr + p * 8192) = gh[p];  // ds_write_b128, swizzled
    }
    __syncthreads();                       // tiles ready

    // issue next step's global loads; latency hides under frag-reads+MFMA
    if (s < 31) {
      const int so = (s + 1) * 64;
      #pragma unroll
      for (int p = 0; p < 4; ++p) {
        ga[p] = __builtin_nontemporal_load((const int4v*)(agp + (size_t)p * 262144 + so));
        gh[p] = *(const short8*)(hgp + (size_t)p * 524288 + so);
      }
      ge0 = *(const float4v*)(efp + so);
      ge1 = *(const float4v*)(efp + so + 2);
    }

    // frag reads (swizzled, conflict-free) + MFMA
    #pragma unroll
    for (int kk = 0; kk < 2; ++kk) {
      const int ko = (kk * 64 + lk8 * 2) ^ fswz;
      short8 af[4], bf[4];
      #pragma unroll
      for (int mi = 0; mi < 4; ++mi) af[mi] = *(const short8*)(ard + mi * 2048 + ko);
      #pragma unroll
      for (int ni = 0; ni < 4; ++ni) bf[ni] = *(const short8*)(brd + ni * 2048 + ko);
      #pragma unroll
      for (int mi = 0; mi < 4; ++mi)
        #pragma unroll
        for (int ni = 0; ni < 4; ++ni)
          acc[mi][ni] = __builtin_amdgcn_mfma_f32_16x16x32_bf16(af[mi], bf[ni], acc[mi][ni], 0, 0, 0);
      if (wn == 0) {
        #pragma unroll
        for (int mi = 0; mi < 4; ++mi)
          accz[mi] = __builtin_amdgcn_mfma_f32_16x16x32_bf16(af[mi], bone, accz[mi], 0, 0, 0);
      }
    }
  }

  // epilogue: split-K partials via atomics
  const int r0 = (lane >> 4) << 2;
  #pragma unroll
  for (int mi = 0; mi < 4; ++mi) {
    const int rowb = I0 + wm * 64 + mi * 16 + r0;
    #pragma unroll
    for (int ni = 0; ni < 4; ++ni) {
      const int col = wn * 64 + ni * 16 + lrow;
      #pragma unroll
      for (int r = 0; r < 4; ++r)
        atomicAdd(&Nout[(size_t)(rowb + r) * 256 + col], acc[mi][ni][r]);
    }
  }
  if (wn == 0 && lrow == 0) {
    #pragma unroll
    for (int mi = 0; mi < 4; ++mi) {
      const int rowb = I0 + wm * 64 + mi * 16 + r0;
      #pragma unroll
      for (int r = 0; r < 4; ++r)
        atomicAdd(&Zp[rowb + r], accz[mi][r]);
    }
  }
}

// ---------------------------------------------------------------------------
// Kernel 5: in-place epilogue on d_out: out = elu(N/Z)
// ---------------------------------------------------------------------------
__global__ __launch_bounds__(256) void k_out(
    float* __restrict__ Nout, const float* __restrict__ Zp) {
  const int idx = blockIdx.x * 256 + threadIdx.x;   // float4 index
  const int i = idx >> 6;                           // row (256 feat = 64 f4)
  const float rz = 1.0f / Zp[i];
  float4v n = ((const float4v*)Nout)[idx];
  float4v o;
  #pragma unroll
  for (int e = 0; e < 4; ++e) {
    float v = n[e] * rz;
    o[e] = (v > 0.f) ? v : expm1f(v);
  }
  ((float4v*)Nout)[idx] = o;
}

// ---------------------------------------------------------------------------
extern "C" void kernel_launch(void* const* d_in, const int* in_sizes, int n_in,
                              void* d_out, int out_size, void* d_ws, size_t ws_size,
                              hipStream_t stream) {
  const int*   adj = (const int*)d_in[0];
  const float* x   = (const float*)d_in[1];
  const float* w   = (const float*)d_in[2];
  const float* a   = (const float*)d_in[3];

  // ws usage: ~4.3 MiB (proven-safe bound). hTf (8 MiB f32) lives in d_out
  // transiently; d_out is then zeroed and used as the f32 N accumulator,
  // finished in place by k_out.
  char* ws = (char*)d_ws;
  short*  hT   = (short*)(ws + 0);          // 4 MiB  bf16 h^T [256][8192]
  float*  t1p  = (float*)(ws + 4194304);    // 64 KiB (2 x 8192)
  float*  t2p  = (float*)(ws + 4259840);    // 64 KiB
  float2* e1f1 = (float2*)(ws + 4325376);   // 64 KiB
  float2* ef2  = (float2*)(ws + 4390912);   // 64 KiB
  float*  Zp   = (float*)(ws + 4456448);    // 32 KiB
  float*  hTf  = (float*)d_out;             // 8 MiB  f32 h^T (transient)
  float*  Nout = (float*)d_out;             // then f32 N accumulator

  k_hgemm  <<<128, 256, 0, stream>>>(x, w, hT, hTf);
  k_scores1<<<dim3(32, 2), 256, 0, stream>>>(hTf, a, t1p, t2p);
  k_scores2<<<32, 256, 0, stream>>>(t1p, t2p, e1f1, ef2);
  hipMemsetAsync(d_out, 0, (size_t)out_size * 4, stream);
  hipMemsetAsync(Zp, 0, 32768, stream);
  k_gat    <<<dim3(64, 4), 512, 0, stream>>>(adj, hT, e1f1, ef2, Nout, Zp);
  k_out    <<<2048, 256, 0, stream>>>(Nout, Zp);
}